// Round 13
// baseline (175.987 us; speedup 1.0000x reference)
//
#include <hip/hip_runtime.h>

// Varifold loss, round 13: 32x32x16 f16 MFMA; FOUR i-tiles per wave
// (block = 512-row panel) -> one B-chunk load feeds 8 MFMAs / 4096 pairs
// per wave-iter, halving non-exp cost per pair again. Epilogues
// interleaved between MFMA pairs to cap live C-frags; launch_bounds(256,4).
//
// t_ij = cq_i + cq_j + TG*<C_i,C_j>;  d_ij = <m_i,m_j>;  term = exp2(t)*d^2.
// A-op K=16: [TGh(3),TGl(3),TGh(3),TGl(3),cqh,cql,1,1]
// B-op K=16: [Ch(3),Ch(3),Cl(3),Cl(3),1,1,cqh,cql]
// d:  A=[mh,ml,mh,ml,0^4], B=[mh,mh,ml,ml,0^4]   (exact hi/lo split)

#define NVERT 5023
#define NFACE 9976
#define BATCH 4
#define HALFP 10240            // per-mesh faces padded: 20 panels x 512
#define NTP   (2 * HALFP)      // 20480 faces per batch
#define NTOT  (BATCH * NTP)    // 81920
#define NCH   640              // j-chunks of 32 per batch
#define NPAN  40               // i-panels of 512
#define SPLITS 26

constexpr float GAMMA = 1.0f / (0.03f * 0.03f);
constexpr float LOG2E = 1.4426950408889634f;
constexpr float EPSV  = 1e-12f;

typedef _Float16 half8_t  __attribute__((ext_vector_type(8)));
typedef float    f32x16   __attribute__((ext_vector_type(16)));
typedef float    f32x2    __attribute__((ext_vector_type(2)));

__global__ __launch_bounds__(256)
void face_quant_kernel(const float* __restrict__ pred,
                       const float* __restrict__ targ,
                       const int*   __restrict__ faces,
                       _Float16*    __restrict__ fd,
                       float*       __restrict__ out) {
    int idx = blockIdx.x * 256 + threadIdx.x;
    if (idx == 0) out[0] = 0.0f;
    if (idx >= NTOT) return;

    int b     = idx / NTP;
    int s     = idx - b * NTP;
    int which = (s >= HALFP) ? 1 : 0;
    int f     = s - which * HALFP;

    _Float16* arec = fd + (size_t)idx * 32;
    _Float16* brec = fd + (size_t)NTOT * 32 + (size_t)idx * 32;

    if (f >= NFACE) {
        half8_t z = {};
        *(half8_t*)(arec + 0) = z; *(half8_t*)(arec + 8)  = z;
        *(half8_t*)(arec + 16) = z; *(half8_t*)(arec + 24) = z;
        *(half8_t*)(brec + 0) = z; *(half8_t*)(brec + 8)  = z;
        *(half8_t*)(brec + 16) = z; *(half8_t*)(brec + 24) = z;
        return;
    }

    const float* V = (which ? targ : pred) + (size_t)b * NVERT * 3;
    int i0 = faces[f * 3 + 0];
    int i1 = faces[f * 3 + 1];
    int i2 = faces[f * 3 + 2];

    float v0x = V[i0*3+0], v0y = V[i0*3+1], v0z = V[i0*3+2];
    float v1x = V[i1*3+0], v1y = V[i1*3+1], v1z = V[i1*3+2];
    float v2x = V[i2*3+0], v2y = V[i2*3+1], v2z = V[i2*3+2];

    const float third = 1.0f / 3.0f;
    float cx = (v0x + v1x + v2x) * third;
    float cy = (v0y + v1y + v2y) * third;
    float cz = (v0z + v1z + v2z) * third;

    float e1x = v1x - v0x, e1y = v1y - v0y, e1z = v1z - v0z;
    float e2x = v2x - v0x, e2y = v2y - v0y, e2z = v2z - v0z;

    float nx = 0.5f * (e1y * e2z - e1z * e2y);
    float ny = 0.5f * (e1z * e2x - e1x * e2z);
    float nz = 0.5f * (e1x * e2y - e1y * e2x);

    float L   = sqrtf(nx*nx + ny*ny + nz*nz);
    float inv = 1.0f / fmaxf(L, EPSV);
    float sc  = inv * sqrtf(L);            // m = Nn*sqrt(L)
    float mx = nx * sc, my = ny * sc, mz = nz * sc;

    const float TG = 2.0f * GAMMA * LOG2E;
    float tgx = TG * cx, tgy = TG * cy, tgz = TG * cz;
    float cq  = -GAMMA * LOG2E * (cx*cx + cy*cy + cz*cz);

    _Float16 TGxh = (_Float16)tgx; _Float16 TGxl = (_Float16)(tgx - (float)TGxh);
    _Float16 TGyh = (_Float16)tgy; _Float16 TGyl = (_Float16)(tgy - (float)TGyh);
    _Float16 TGzh = (_Float16)tgz; _Float16 TGzl = (_Float16)(tgz - (float)TGzh);
    _Float16 Cxh  = (_Float16)cx;  _Float16 Cxl  = (_Float16)(cx  - (float)Cxh);
    _Float16 Cyh  = (_Float16)cy;  _Float16 Cyl  = (_Float16)(cy  - (float)Cyh);
    _Float16 Czh  = (_Float16)cz;  _Float16 Czl  = (_Float16)(cz  - (float)Czh);
    _Float16 cqh  = (_Float16)cq;  _Float16 cql  = (_Float16)(cq  - (float)cqh);
    _Float16 mxh  = (_Float16)mx;  _Float16 mxl  = (_Float16)(mx  - (float)mxh);
    _Float16 myh  = (_Float16)my;  _Float16 myl  = (_Float16)(my  - (float)myh);
    _Float16 mzh  = (_Float16)mz;  _Float16 mzl  = (_Float16)(mz  - (float)mzh);
    _Float16 one  = (_Float16)1.0f;
    _Float16 zz   = (_Float16)0.0f;

    half8_t ta0 = {TGxh, TGyh, TGzh, TGxl, TGyl, TGzl, TGxh, TGyh};
    half8_t ta1 = {TGzh, TGxl, TGyl, TGzl, cqh,  cql,  one,  one };
    half8_t da0 = {mxh,  myh,  mzh,  mxl,  myl,  mzl,  mxh,  myh };
    half8_t da1 = {mzh,  mxl,  myl,  mzl,  zz,   zz,   zz,   zz  };
    half8_t tb0 = {Cxh,  Cyh,  Czh,  Cxh,  Cyh,  Czh,  Cxl,  Cyl };
    half8_t tb1 = {Czl,  Cxl,  Cyl,  Czl,  one,  one,  cqh,  cql };
    half8_t db0 = {mxh,  myh,  mzh,  mxh,  myh,  mzh,  mxl,  myl };
    half8_t db1 = {mzl,  mxl,  myl,  mzl,  zz,   zz,   zz,   zz  };

    *(half8_t*)(arec + 0)  = ta0;  *(half8_t*)(arec + 8)  = ta1;
    *(half8_t*)(arec + 16) = da0;  *(half8_t*)(arec + 24) = da1;
    *(half8_t*)(brec + 0)  = tb0;  *(half8_t*)(brec + 8)  = tb1;
    *(half8_t*)(brec + 16) = db0;  *(half8_t*)(brec + 24) = db1;
}

__device__ __forceinline__ half8_t ld8(const _Float16* p) {
    return *(const half8_t*)p;
}

__global__ __launch_bounds__(256, 4)
void pair_sum_kernel(const _Float16* __restrict__ fd,
                     float*          __restrict__ out) {
    const int b       = blockIdx.z;
    const int pairIdx = blockIdx.x / SPLITS;     // 0..19
    const int s       = blockIdx.x % SPLITS;

    const _Float16* Arec = fd;
    const _Float16* Brec = fd + (size_t)NTOT * 32;

    const int lane = threadIdx.x & 63;
    const int w    = threadIdx.x >> 6;
    const int col  = lane & 31;
    const int koff = (lane >> 5) * 8;

    const size_t bface = (size_t)b * NTP;
    const size_t JSTEP = (size_t)SPLITS * 32 * 32;

    float acc = 0.0f;

    #pragma unroll 1
    for (int h = 0; h < 2; ++h) {
        const int   P  = h ? (NPAN - 1 - pairIdx) : pairIdx;
        const int   c0 = 16 * P;
        const float si = (P < NPAN / 2) ? 1.0f : -1.0f;
        const int   iters = (NCH - c0 - s + SPLITS - 1) / SPLITS;
        if (iters <= 0) continue;

        // four i-tiles per wave: rows P*512 + w*32 + t*128
        const _Float16* ap0 = Arec + (bface + (size_t)(P * 512 + w * 32 + col)) * 32 + koff;
        half8_t aT0 = ld8(ap0);                 half8_t aD0 = ld8(ap0 + 16);
        half8_t aT1 = ld8(ap0 + 128 * 32);      half8_t aD1 = ld8(ap0 + 128 * 32 + 16);
        half8_t aT2 = ld8(ap0 + 256 * 32);      half8_t aD2 = ld8(ap0 + 256 * 32 + 16);
        half8_t aT3 = ld8(ap0 + 384 * 32);      half8_t aD3 = ld8(ap0 + 384 * 32 + 16);

        const _Float16* pB = Brec + (bface + (size_t)((c0 + s) * 32 + col)) * 32 + koff;
        half8_t bT = ld8(pB);
        half8_t bD = ld8(pB + 16);

        f32x16 z = {};

        #define EPI(T_, D_, ts_)                                               \
        {                                                                      \
            _Pragma("unroll")                                                  \
            for (int r = 0; r < 16; r += 2) {                                  \
                f32x2 ee = {__builtin_amdgcn_exp2f((T_)[r]),                   \
                            __builtin_amdgcn_exp2f((T_)[r + 1])};              \
                f32x2 dd = {(D_)[r], (D_)[r + 1]};                             \
                dd = dd * dd;                                                  \
                ts_ = ee * dd + ts_;                                           \
            }                                                                  \
        }

        #pragma unroll 1
        for (int k = 0; k < iters; ++k) {
            // depth-1 branchless prefetch of next chunk (clamped)
            const _Float16* pN = (k + 1 < iters) ? (pB + JSTEP) : pB;
            half8_t nT = ld8(pN);
            half8_t nD = ld8(pN + 16);
            pB = pN;

            f32x2 ts = {0.f, 0.f};

            f32x16 T0 = __builtin_amdgcn_mfma_f32_32x32x16_f16(aT0, bT, z, 0, 0, 0);
            f32x16 D0 = __builtin_amdgcn_mfma_f32_32x32x16_f16(aD0, bD, z, 0, 0, 0);
            f32x16 T1 = __builtin_amdgcn_mfma_f32_32x32x16_f16(aT1, bT, z, 0, 0, 0);
            f32x16 D1 = __builtin_amdgcn_mfma_f32_32x32x16_f16(aD1, bD, z, 0, 0, 0);
            EPI(T0, D0, ts);
            f32x16 T2 = __builtin_amdgcn_mfma_f32_32x32x16_f16(aT2, bT, z, 0, 0, 0);
            f32x16 D2 = __builtin_amdgcn_mfma_f32_32x32x16_f16(aD2, bD, z, 0, 0, 0);
            EPI(T1, D1, ts);
            f32x16 T3 = __builtin_amdgcn_mfma_f32_32x32x16_f16(aT3, bT, z, 0, 0, 0);
            f32x16 D3 = __builtin_amdgcn_mfma_f32_32x32x16_f16(aD3, bD, z, 0, 0, 0);
            EPI(T2, D2, ts);
            EPI(T3, D3, ts);

            const int   jc  = c0 + s + SPLITS * k;
            const float sj  = (jc < NCH / 2) ? si : -si;
            const float wgt = (k == 0 && s < 16) ? 1.0f : 2.0f;
            acc = fmaf(sj * wgt, ts.x + ts.y, acc);

            bT = nT; bD = nD;
        }
        #undef EPI
    }

    acc *= (1.0f / BATCH);

    #pragma unroll
    for (int off = 32; off > 0; off >>= 1)
        acc += __shfl_down(acc, off, 64);

    __shared__ float wsum[4];
    if (lane == 0) wsum[w] = acc;
    __syncthreads();
    if (threadIdx.x == 0)
        atomicAdd(out, wsum[0] + wsum[1] + wsum[2] + wsum[3]);
}

extern "C" void kernel_launch(void* const* d_in, const int* in_sizes, int n_in,
                              void* d_out, int out_size, void* d_ws, size_t ws_size,
                              hipStream_t stream) {
    const float* pred  = (const float*)d_in[0];
    const float* targ  = (const float*)d_in[1];
    const int*   faces = (const int*)d_in[2];
    float*       out   = (float*)d_out;
    _Float16*    fd    = (_Float16*)d_ws;   // 2 arrays x 81920 faces x 64 B = 10.5 MB

    face_quant_kernel<<<(NTOT + 255) / 256, 256, 0, stream>>>(
        pred, targ, faces, fd, out);

    dim3 grid((NPAN / 2) * SPLITS, 1, BATCH);   // 520 x 1 x 4 = 2080 blocks
    pair_sum_kernel<<<grid, 256, 0, stream>>>(fd, out);
}

// Round 14
// 157.289 us; speedup vs baseline: 1.1189x; 1.1189x over previous
//
#include <hip/hip_runtime.h>

// Varifold loss, round 14: REVERT to R12 (measured optimum: 157.1 µs total,
// 109.7 µs pair). R13 (4 i-tiles) regressed via register/occupancy cliff
// (140 regs > 128 -> 3 waves/EU); R8-R11 probes all inferior. R12 sits at
// the 4-waves/EU boundary with 2 i-tiles/wave, 4 MFMAs / 2048 pairs per
// B-chunk load, depth-1 branchless prefetch, packed epilogue.
//
// t_ij = cq_i + cq_j + TG*<C_i,C_j>;  d_ij = <m_i,m_j>;  term = exp2(t)*d^2.
// A-op K=16: [TGh(3),TGl(3),TGh(3),TGl(3),cqh,cql,1,1]
// B-op K=16: [Ch(3),Ch(3),Cl(3),Cl(3),1,1,cqh,cql]
// d:  A=[mh,ml,mh,ml,0^4], B=[mh,mh,ml,ml,0^4]   (exact hi/lo split)

#define NVERT 5023
#define NFACE 9976
#define BATCH 4
#define HALFP 9984             // per-mesh faces padded: 39 panels x 256
#define NTP   (2 * HALFP)      // 19968 faces per batch
#define NTOT  (BATCH * NTP)    // 79872
#define NCH   624              // j-chunks of 32 per batch
#define NPAN  78               // i-panels of 256
#define SPLITS 26

constexpr float GAMMA = 1.0f / (0.03f * 0.03f);
constexpr float LOG2E = 1.4426950408889634f;
constexpr float EPSV  = 1e-12f;

typedef _Float16 half8_t  __attribute__((ext_vector_type(8)));
typedef float    f32x16   __attribute__((ext_vector_type(16)));
typedef float    f32x2    __attribute__((ext_vector_type(2)));

__global__ __launch_bounds__(256)
void face_quant_kernel(const float* __restrict__ pred,
                       const float* __restrict__ targ,
                       const int*   __restrict__ faces,
                       _Float16*    __restrict__ fd,
                       float*       __restrict__ out) {
    int idx = blockIdx.x * 256 + threadIdx.x;
    if (idx == 0) out[0] = 0.0f;
    if (idx >= NTOT) return;

    int b     = idx / NTP;
    int s     = idx - b * NTP;
    int which = (s >= HALFP) ? 1 : 0;
    int f     = s - which * HALFP;

    _Float16* arec = fd + (size_t)idx * 32;
    _Float16* brec = fd + (size_t)NTOT * 32 + (size_t)idx * 32;

    if (f >= NFACE) {
        half8_t z = {};
        *(half8_t*)(arec + 0) = z; *(half8_t*)(arec + 8)  = z;
        *(half8_t*)(arec + 16) = z; *(half8_t*)(arec + 24) = z;
        *(half8_t*)(brec + 0) = z; *(half8_t*)(brec + 8)  = z;
        *(half8_t*)(brec + 16) = z; *(half8_t*)(brec + 24) = z;
        return;
    }

    const float* V = (which ? targ : pred) + (size_t)b * NVERT * 3;
    int i0 = faces[f * 3 + 0];
    int i1 = faces[f * 3 + 1];
    int i2 = faces[f * 3 + 2];

    float v0x = V[i0*3+0], v0y = V[i0*3+1], v0z = V[i0*3+2];
    float v1x = V[i1*3+0], v1y = V[i1*3+1], v1z = V[i1*3+2];
    float v2x = V[i2*3+0], v2y = V[i2*3+1], v2z = V[i2*3+2];

    const float third = 1.0f / 3.0f;
    float cx = (v0x + v1x + v2x) * third;
    float cy = (v0y + v1y + v2y) * third;
    float cz = (v0z + v1z + v2z) * third;

    float e1x = v1x - v0x, e1y = v1y - v0y, e1z = v1z - v0z;
    float e2x = v2x - v0x, e2y = v2y - v0y, e2z = v2z - v0z;

    float nx = 0.5f * (e1y * e2z - e1z * e2y);
    float ny = 0.5f * (e1z * e2x - e1x * e2z);
    float nz = 0.5f * (e1x * e2y - e1y * e2x);

    float L   = sqrtf(nx*nx + ny*ny + nz*nz);
    float inv = 1.0f / fmaxf(L, EPSV);
    float sc  = inv * sqrtf(L);            // m = Nn*sqrt(L)
    float mx = nx * sc, my = ny * sc, mz = nz * sc;

    const float TG = 2.0f * GAMMA * LOG2E;
    float tgx = TG * cx, tgy = TG * cy, tgz = TG * cz;
    float cq  = -GAMMA * LOG2E * (cx*cx + cy*cy + cz*cz);

    _Float16 TGxh = (_Float16)tgx; _Float16 TGxl = (_Float16)(tgx - (float)TGxh);
    _Float16 TGyh = (_Float16)tgy; _Float16 TGyl = (_Float16)(tgy - (float)TGyh);
    _Float16 TGzh = (_Float16)tgz; _Float16 TGzl = (_Float16)(tgz - (float)TGzh);
    _Float16 Cxh  = (_Float16)cx;  _Float16 Cxl  = (_Float16)(cx  - (float)Cxh);
    _Float16 Cyh  = (_Float16)cy;  _Float16 Cyl  = (_Float16)(cy  - (float)Cyh);
    _Float16 Czh  = (_Float16)cz;  _Float16 Czl  = (_Float16)(cz  - (float)Czh);
    _Float16 cqh  = (_Float16)cq;  _Float16 cql  = (_Float16)(cq  - (float)cqh);
    _Float16 mxh  = (_Float16)mx;  _Float16 mxl  = (_Float16)(mx  - (float)mxh);
    _Float16 myh  = (_Float16)my;  _Float16 myl  = (_Float16)(my  - (float)myh);
    _Float16 mzh  = (_Float16)mz;  _Float16 mzl  = (_Float16)(mz  - (float)mzh);
    _Float16 one  = (_Float16)1.0f;
    _Float16 zz   = (_Float16)0.0f;

    half8_t ta0 = {TGxh, TGyh, TGzh, TGxl, TGyl, TGzl, TGxh, TGyh};
    half8_t ta1 = {TGzh, TGxl, TGyl, TGzl, cqh,  cql,  one,  one };
    half8_t da0 = {mxh,  myh,  mzh,  mxl,  myl,  mzl,  mxh,  myh };
    half8_t da1 = {mzh,  mxl,  myl,  mzl,  zz,   zz,   zz,   zz  };
    half8_t tb0 = {Cxh,  Cyh,  Czh,  Cxh,  Cyh,  Czh,  Cxl,  Cyl };
    half8_t tb1 = {Czl,  Cxl,  Cyl,  Czl,  one,  one,  cqh,  cql };
    half8_t db0 = {mxh,  myh,  mzh,  mxh,  myh,  mzh,  mxl,  myl };
    half8_t db1 = {mzl,  mxl,  myl,  mzl,  zz,   zz,   zz,   zz  };

    *(half8_t*)(arec + 0)  = ta0;  *(half8_t*)(arec + 8)  = ta1;
    *(half8_t*)(arec + 16) = da0;  *(half8_t*)(arec + 24) = da1;
    *(half8_t*)(brec + 0)  = tb0;  *(half8_t*)(brec + 8)  = tb1;
    *(half8_t*)(brec + 16) = db0;  *(half8_t*)(brec + 24) = db1;
}

__device__ __forceinline__ half8_t ld8(const _Float16* p) {
    return *(const half8_t*)p;
}

__global__ __launch_bounds__(256, 4)
void pair_sum_kernel(const _Float16* __restrict__ fd,
                     float*          __restrict__ out) {
    const int b       = blockIdx.z;
    const int pairIdx = blockIdx.x / SPLITS;     // 0..38
    const int s       = blockIdx.x % SPLITS;

    const _Float16* Arec = fd;
    const _Float16* Brec = fd + (size_t)NTOT * 32;

    const int lane = threadIdx.x & 63;
    const int w    = threadIdx.x >> 6;
    const int col  = lane & 31;
    const int koff = (lane >> 5) * 8;

    const size_t bface = (size_t)b * NTP;
    const size_t JSTEP = (size_t)SPLITS * 32 * 32;

    float acc = 0.0f;

    #pragma unroll 1
    for (int h = 0; h < 2; ++h) {
        const int   P  = h ? (NPAN - 1 - pairIdx) : pairIdx;
        const int   c0 = 8 * P;
        const float si = (P < NPAN / 2) ? 1.0f : -1.0f;
        const int   iters = (NCH - c0 - s + SPLITS - 1) / SPLITS;
        if (iters <= 0) continue;

        // two i-tiles per wave: rows P*256 + w*32 (+128)
        const _Float16* ap0 = Arec + (bface + (size_t)(P * 256 + w * 32 + col)) * 32 + koff;
        const _Float16* ap1 = ap0 + (size_t)128 * 32;
        half8_t aT0 = ld8(ap0);
        half8_t aD0 = ld8(ap0 + 16);
        half8_t aT1 = ld8(ap1);
        half8_t aD1 = ld8(ap1 + 16);

        const _Float16* pB = Brec + (bface + (size_t)((c0 + s) * 32 + col)) * 32 + koff;
        half8_t bT = ld8(pB);
        half8_t bD = ld8(pB + 16);

        f32x16 z = {};

        #pragma unroll 1
        for (int k = 0; k < iters; ++k) {
            // depth-1 branchless prefetch of next chunk (clamped)
            const _Float16* pN = (k + 1 < iters) ? (pB + JSTEP) : pB;
            half8_t nT = ld8(pN);
            half8_t nD = ld8(pN + 16);
            pB = pN;

            // one B-chunk feeds both i-tiles: 4 MFMAs / 2048 pairs
            f32x16 T0 = __builtin_amdgcn_mfma_f32_32x32x16_f16(aT0, bT, z, 0, 0, 0);
            f32x16 D0 = __builtin_amdgcn_mfma_f32_32x32x16_f16(aD0, bD, z, 0, 0, 0);
            f32x16 T1 = __builtin_amdgcn_mfma_f32_32x32x16_f16(aT1, bT, z, 0, 0, 0);
            f32x16 D1 = __builtin_amdgcn_mfma_f32_32x32x16_f16(aD1, bD, z, 0, 0, 0);

            // two independent packed epilogues
            f32x2 ts0 = {0.f, 0.f}, ts1 = {0.f, 0.f};
            #pragma unroll
            for (int r = 0; r < 16; r += 2) {
                f32x2 e0 = {__builtin_amdgcn_exp2f(T0[r]),
                            __builtin_amdgcn_exp2f(T0[r + 1])};
                f32x2 d0 = {D0[r], D0[r + 1]};
                d0 = d0 * d0;
                ts0 = e0 * d0 + ts0;
                f32x2 e1 = {__builtin_amdgcn_exp2f(T1[r]),
                            __builtin_amdgcn_exp2f(T1[r + 1])};
                f32x2 d1 = {D1[r], D1[r + 1]};
                d1 = d1 * d1;
                ts1 = e1 * d1 + ts1;
            }

            const int   jc  = c0 + s + SPLITS * k;
            const float sj  = (jc < NCH / 2) ? si : -si;
            const float wgt = (k == 0 && s < 8) ? 1.0f : 2.0f;
            acc = fmaf(sj * wgt, ts0.x + ts0.y + ts1.x + ts1.y, acc);

            bT = nT; bD = nD;
        }
    }

    acc *= (1.0f / BATCH);

    #pragma unroll
    for (int off = 32; off > 0; off >>= 1)
        acc += __shfl_down(acc, off, 64);

    __shared__ float wsum[4];
    if (lane == 0) wsum[w] = acc;
    __syncthreads();
    if (threadIdx.x == 0)
        atomicAdd(out, wsum[0] + wsum[1] + wsum[2] + wsum[3]);
}

extern "C" void kernel_launch(void* const* d_in, const int* in_sizes, int n_in,
                              void* d_out, int out_size, void* d_ws, size_t ws_size,
                              hipStream_t stream) {
    const float* pred  = (const float*)d_in[0];
    const float* targ  = (const float*)d_in[1];
    const int*   faces = (const int*)d_in[2];
    float*       out   = (float*)d_out;
    _Float16*    fd    = (_Float16*)d_ws;   // 2 arrays x 79872 faces x 64 B = 10.2 MB

    face_quant_kernel<<<(NTOT + 255) / 256, 256, 0, stream>>>(
        pred, targ, faces, fd, out);

    dim3 grid((NPAN / 2) * SPLITS, 1, BATCH);   // 1014 x 1 x 4 = 4056 blocks
    pair_sum_kernel<<<grid, 256, 0, stream>>>(fd, out);
}